// Round 1
// 360.944 us; speedup vs baseline: 1.0661x; 1.0661x over previous
//
#include <hip/hip_runtime.h>
#include <stdint.h>

// SCC (sliding-channel conv) = 8 dense group-GEMMs (o%8==g reads channel band
// [128g,128g+256) mod 1024). bf16 MFMA 16x16x32.
// R3: barrier-free main loop.
//   - Prologue kernel pre-converts W fp32->bf16 into d_ws, laid out as 8
//     per-g 64KB LDS images, XOR-swizzled (seg ^ (m&7)) so ds_read_b128
//     A-frag reads are 2-way-max on banks (free).
//   - Main kernel: stage whole W slice once (16 linear int4 copies), ONE
//     __syncthreads, then a pure k-loop: x global->reg (4-kb-deep prefetch,
//     loads stay in flight -- no barriers drain vmcnt), f2bf, ds_read, MFMA.
//   - acc fp32; wave = M128 x N16 strip; block = 128x64 out tile.

#define B_      16
#define C_IN    1024
#define C_OUT   1024
#define UNIT    256
#define STRIDE_ 128
#define HW      3136
#define NT      64      // spatial tile: 3136 = 49*64 exact

typedef __attribute__((ext_vector_type(8))) short bf16x8;
typedef __attribute__((ext_vector_type(4))) float floatx4;
typedef __attribute__((ext_vector_type(4))) short short4v;

__device__ __forceinline__ short f2bf(float f) {
    // fp32 -> bf16, round-to-nearest-even
    uint32_t u = __float_as_uint(f);
    u += 0x7FFFu + ((u >> 16) & 1u);
    return (short)(u >> 16);
}

// ---- prologue: W [1024][256] fp32 -> d_ws, 8 x 64KB swizzled bf16 images.
// Image g, row m (o = g+8m), 32 segments of 8 bf16; segment seg stored at
// slot (seg ^ (m&7)) within the 512B row.
__global__ __launch_bounds__(256) void w_pack_kernel(
    const float* __restrict__ w, short* __restrict__ wp)
{
    int t   = blockIdx.x * 256 + threadIdx.x;   // 65536 threads x 4 floats
    int o   = t >> 6;                           // 0..1023
    int kk4 = (t & 63) << 2;                    // 0..252
    int g = o & 7, m = o >> 3;
    float4 v = *(const float4*)(w + ((size_t)o << 8) + kk4);
    short4v s4 = { f2bf(v.x), f2bf(v.y), f2bf(v.z), f2bf(v.w) };
    int seg = kk4 >> 3;
    char* dst = (char*)wp + ((size_t)(g * 128 + m) << 9)
              + (((seg ^ (m & 7)) << 4) | ((kk4 & 4) << 1));
    *(short4v*)dst = s4;
}

template <bool PRE>
__global__ __launch_bounds__(256, 2) void scc_mfma_kernel(
    const float* __restrict__ x, const float* __restrict__ w,
    const short* __restrict__ wp, float* __restrict__ out)
{
    __shared__ short Ws[128 * 256];  // 64 KB bf16, full K, XOR-swizzled rows

    const int tid  = threadIdx.x;
    const int lane = tid & 63;
    const int wn   = tid >> 6;       // wave = one 16-wide N strip
    const int nq   = lane & 15;      // MFMA n-col / A-row index
    const int quad = lane >> 4;      // MFMA k-group

    const int p0 = blockIdx.x * NT;
    const int g  = blockIdx.y;
    const int b  = blockIdx.z;

    const int    p  = p0 + wn * 16 + nq;
    const float* xb = x + (size_t)b * C_IN * HW + p;

    // ---- issue x loads for kb=0..3 FIRST: their HBM latency hides under
    // the W staging + barrier below.
    float bv[8][8];
#pragma unroll
    for (int kb = 0; kb < 4; ++kb) {
        int cb = (g * STRIDE_ + kb * 32 + quad * 8) & (C_IN - 1);
        const float* xp = xb + (size_t)cb * HW;
#pragma unroll
        for (int j = 0; j < 8; ++j) bv[kb][j] = xp[(size_t)j * HW];
    }

    // ---- stage the whole W slice once
    char* wsb = (char*)Ws;
    if (PRE) {
        // pre-swizzled bf16 image in workspace: plain linear 64KB copy
        const char* ws = (const char*)(wp + (size_t)g * 32768);
#pragma unroll
        for (int i = 0; i < 16; ++i) {
            int4 v = *(const int4*)(ws + i * 4096 + tid * 16);
            *(int4*)(wsb + i * 4096 + tid * 16) = v;
        }
    } else {
        // fallback: convert fp32 W in-kernel (ws too small)
#pragma unroll
        for (int r = 0; r < 32; ++r) {
            int f   = tid + 256 * r;          // 0..8191 float4s
            int m   = f >> 6;                 // 0..127
            int kk4 = (f & 63) << 2;          // 0..252
            float4 v = *(const float4*)(w + (size_t)(g + 8 * m) * UNIT + kk4);
            short4v s4 = { f2bf(v.x), f2bf(v.y), f2bf(v.z), f2bf(v.w) };
            int seg = kk4 >> 3;
            *(short4v*)(wsb + m * 512 + (((seg ^ (m & 7)) << 4) | ((kk4 & 4) << 1))) = s4;
        }
    }

    floatx4 acc[8];
#pragma unroll
    for (int i = 0; i < 8; ++i) acc[i] = (floatx4){0.f, 0.f, 0.f, 0.f};

    __syncthreads();   // the ONLY barrier: Ws valid, bv[0..3] resident

    // ---- barrier-free k-loop: 8 k-steps of 32; prefetch kb+4 while
    // computing kb (loads stay outstanding across iterations).
#pragma unroll
    for (int kb = 0; kb < 8; ++kb) {
        if (kb < 4) {
            int cb = (g * STRIDE_ + (kb + 4) * 32 + quad * 8) & (C_IN - 1);
            const float* xp = xb + (size_t)cb * HW;
#pragma unroll
            for (int j = 0; j < 8; ++j) bv[kb + 4][j] = xp[(size_t)j * HW];
        }
        bf16x8 bfrag;
#pragma unroll
        for (int j = 0; j < 8; ++j) bfrag[j] = f2bf(bv[kb][j]);
        const int aoff = nq * 512 + (((kb * 4 + quad) ^ (nq & 7)) << 4);
#pragma unroll
        for (int mf = 0; mf < 8; ++mf) {
            bf16x8 afrag = *(const bf16x8*)(wsb + mf * 8192 + aoff);
            acc[mf] = __builtin_amdgcn_mfma_f32_16x16x32_bf16(afrag, bfrag, acc[mf], 0, 0, 0);
        }
    }

    // ---- epilogue: D col = nq (=p), row = quad*4 + reg within each 16-block;
    // o = g + 8*(mf*16 + quad*4 + reg) = g + 128*mf + 32*quad + 8*reg
    float* ob = out + ((size_t)b * C_OUT + g + 32 * quad) * HW + p;
#pragma unroll
    for (int mf = 0; mf < 8; ++mf) {
        float* o2 = ob + (size_t)(128 * mf) * HW;
#pragma unroll
        for (int reg = 0; reg < 4; ++reg)
            o2[(size_t)(8 * reg) * HW] = acc[mf][reg];
    }
}

extern "C" void kernel_launch(void* const* d_in, const int* in_sizes, int n_in,
                              void* d_out, int out_size, void* d_ws, size_t ws_size,
                              hipStream_t stream)
{
    const float* x = (const float*)d_in[0];
    const float* w = (const float*)d_in[1];
    float* out = (float*)d_out;

    dim3 grid(HW / NT, 8, B_);   // (49, 8, 16)
    if (d_ws && ws_size >= (size_t)524288) {
        short* wp = (short*)d_ws;
        w_pack_kernel<<<dim3(256), 256, 0, stream>>>(w, wp);
        scc_mfma_kernel<true><<<grid, 256, 0, stream>>>(x, w, wp, out);
    } else {
        scc_mfma_kernel<false><<<grid, 256, 0, stream>>>(x, w, (const short*)nullptr, out);
    }
}